// Round 4
// baseline (241.115 us; speedup 1.0000x reference)
//
#include <hip/hip_runtime.h>
#include <math.h>

#define BB 4
#define C 256
#define H 64
#define W 64
#define HW 4096
#define HO 128
#define WO 128
#define HWO 16384
#define EMB 64

typedef __bf16 bf16x8 __attribute__((ext_vector_type(8)));
typedef __bf16 bf16x4 __attribute__((ext_vector_type(4)));
typedef float  f32x4  __attribute__((ext_vector_type(4)));

__device__ __forceinline__ f32x4 mfma16(bf16x8 a, bf16x8 b, f32x4 c) {
    return __builtin_amdgcn_mfma_f32_16x16x32_bf16(a, b, c, 0, 0, 0);
}

// ---------------------------------------------------------------------------
// K1: weight tables (bf16)
//   wbf_cen: [e][c] (=w_cen layout, cast)
//   wdec5:   [5mt][16m][256c]; mt<4 = w_cde; mt=4 row0 = w_gate, rest 0
//   w3:      [tap9][mt2][16m][64e], rows m>=25 zeroed
// ---------------------------------------------------------------------------
__global__ void k_prep2(const float* __restrict__ w_cen,
                        const float* __restrict__ w_cde,
                        const float* __restrict__ w_gate,
                        const float* __restrict__ w_ce,
                        __bf16* __restrict__ wbf_cen,
                        __bf16* __restrict__ wdec5,
                        __bf16* __restrict__ w3) {
    for (int idx = blockIdx.x * blockDim.x + threadIdx.x; idx < 16384;
         idx += gridDim.x * blockDim.x)
        wbf_cen[idx] = (__bf16)w_cen[idx];
    for (int idx = blockIdx.x * blockDim.x + threadIdx.x; idx < 20480;
         idx += gridDim.x * blockDim.x) {
        int c = idx & 255, m = (idx >> 8) & 15;
        float v;
        if (idx < 16384) v = w_cde[idx];
        else             v = (m == 0) ? w_gate[c] : 0.f;
        wdec5[idx] = (__bf16)v;
    }
    for (int idx = blockIdx.x * blockDim.x + threadIdx.x; idx < 18432;
         idx += gridDim.x * blockDim.x) {
        int e = idx & 63;
        int m = (idx >> 6) & 15;
        int mt = (idx >> 10) & 1;
        int tap = idx >> 11;
        int q = mt * 16 + m;
        int dy = tap / 3, dx = tap % 3;
        w3[idx] = (q < 25) ? (__bf16)w_ce[((q * EMB + e) * 3 + dy) * 3 + dx]
                           : (__bf16)0.0f;
    }
}

// ---------------------------------------------------------------------------
// K2: MFMA GEMM Y[px][e] = Wt[e][c]·X[c][px], LDS-staged X, 64-px blocks.
//   blocks [0,1024): enc (4 mt, +b_cen); [1024,1280): dec (5 mt; mt4 row0=gate)
// ---------------------------------------------------------------------------
__global__ __launch_bounds__(256) void k_gemm1(
        const float* __restrict__ en, const float* __restrict__ de,
        const __bf16* __restrict__ wbf_cen, const __bf16* __restrict__ wdec5,
        const float* __restrict__ b_cen, const float* __restrict__ b_gate,
        __bf16* __restrict__ enc_t, __bf16* __restrict__ dec_t,
        float* __restrict__ gate_lr) {
    __shared__ float xs[32 * 64];                 // [c32][px64], 8 KB
    int t = threadIdx.x;
    int w = t >> 6, lane = t & 63;
    int n = lane & 15, q = lane >> 4;
    bool isenc = blockIdx.x < 1024;
    const float* X; const __bf16* Wt; __bf16* Y; int plane, px0, b;
    if (isenc) {
        int blk = blockIdx.x; b = blk >> 8; px0 = (blk & 255) << 6;
        X = en + (size_t)b * C * HWO; plane = HWO; Wt = wbf_cen;
        Y = enc_t + (size_t)b * HWO * EMB;
    } else {
        int blk = blockIdx.x - 1024; b = blk >> 6; px0 = (blk & 63) << 6;
        X = de + (size_t)b * C * HW; plane = HW; Wt = wdec5;
        Y = dec_t + (size_t)b * HW * EMB;
    }
    int px = w * 16 + n;
    f32x4 acc[5] = {};
    for (int kc = 0; kc < 8; kc++) {
        int c0 = kc * 32;
        __syncthreads();
        #pragma unroll
        for (int i = 0; i < 2; i++) {
            int idx = i * 256 + t;                // 512 float4s
            int c = idx >> 4, p4 = (idx & 15) << 2;
            float4 v = *(const float4*)(X + (size_t)(c0 + c) * plane + px0 + p4);
            *(float4*)(xs + c * 64 + p4) = v;
        }
        __syncthreads();
        bf16x8 af[5];
        #pragma unroll
        for (int mt = 0; mt < 4; mt++)
            af[mt] = *(const bf16x8*)(Wt + (mt * 16 + n) * C + c0 + q * 8);
        if (!isenc)
            af[4] = *(const bf16x8*)(Wt + (64 + n) * C + c0 + q * 8);
        bf16x8 bv;
        #pragma unroll
        for (int j = 0; j < 8; j++)
            bv[j] = (__bf16)xs[(q * 8 + j) * 64 + px];
        #pragma unroll
        for (int mt = 0; mt < 4; mt++)
            acc[mt] = mfma16(af[mt], bv, acc[mt]);
        if (!isenc)
            acc[4] = mfma16(af[4], bv, acc[4]);
    }
    int gpx = px0 + px;
    #pragma unroll
    for (int mt = 0; mt < 4; mt++) {
        int e0 = mt * 16 + q * 4;
        bf16x4 ov;
        #pragma unroll
        for (int r = 0; r < 4; r++) {
            float bias = isenc ? b_cen[e0 + r] : 0.f;
            ov[r] = (__bf16)(acc[mt][r] + bias);
        }
        *(bf16x4*)(Y + (size_t)gpx * EMB + e0) = ov;
    }
    if (!isenc && q == 0)                          // gate = sigmoid(row 64)
        gate_lr[b * HW + gpx] = 1.f / (1.f + __expf(-(acc[4][0] + b_gate[0])));
}

// ---------------------------------------------------------------------------
// K3: 3x3 conv 64->25 via MFMA; 3 input rows staged in LDS in fragment order
//     (zero-padded halo). blocks [0,1024): enc_t->tmp1; [1024,1280): dec_t->tmp2
// ---------------------------------------------------------------------------
__global__ __launch_bounds__(256) void k_conv3m(
        const __bf16* __restrict__ enc_t, const __bf16* __restrict__ dec_t,
        const __bf16* __restrict__ w3, const float* __restrict__ b_ce,
        float* __restrict__ tmp1, float* __restrict__ tmp2) {
    __shared__ __bf16 sfr[8 * 3 * 66 * 8];        // [kc*4+q][row][xloc][8], 25.3 KB
    int t = threadIdx.x;
    int w = t >> 6, lane = t & 63;
    int n = lane & 15, q = lane >> 4;
    bool hi = blockIdx.x < 1024;
    const __bf16* src; float* dst; int b, y, width, plane, x0;
    if (hi) {
        int blk = blockIdx.x; b = blk >> 8; int r = blk & 255;
        y = r >> 1; x0 = (r & 1) * 64;
        width = WO; plane = HWO;
        src = enc_t + (size_t)b * HWO * EMB; dst = tmp1;
    } else {
        int blk = blockIdx.x - 1024; b = blk >> 6; y = blk & 63; x0 = 0;
        width = W; plane = HW;
        src = dec_t + (size_t)b * HW * EMB; dst = tmp2;
    }
    // stage: idx = (row*66 + xloc)*8 + f  (f = kc*4+q = e>>3), 1584 frags
    bf16x8 zf;
    #pragma unroll
    for (int j = 0; j < 8; j++) zf[j] = (__bf16)0.0f;
    for (int idx = t; idx < 1584; idx += 256) {
        int f = idx & 7;
        int rem = idx >> 3;
        int xloc = rem % 66, row = rem / 66;
        int yy = y + row - 1, xg = x0 - 1 + xloc;
        bf16x8 v = zf;
        if ((unsigned)yy < (unsigned)width && (unsigned)xg < (unsigned)width)
            v = *(const bf16x8*)(src + ((size_t)yy * width + xg) * EMB + f * 8);
        *(bf16x8*)(sfr + (((f * 3) + row) * 66 + xloc) * 8) = v;
    }
    __syncthreads();

    int x = w * 16 + n;
    f32x4 acc[2] = {};
    #pragma unroll
    for (int row = 0; row < 3; row++) {
        #pragma unroll
        for (int dx = 0; dx < 3; dx++) {
            int tap = row * 3 + dx;
            #pragma unroll
            for (int kc = 0; kc < 2; kc++) {
                bf16x8 bv = *(const bf16x8*)(
                    sfr + ((((kc * 4 + q) * 3) + row) * 66 + x + dx) * 8);
                #pragma unroll
                for (int mt = 0; mt < 2; mt++) {
                    bf16x8 av = *(const bf16x8*)(
                        w3 + ((tap * 2 + mt) * 16 + n) * EMB + kc * 32 + q * 8);
                    acc[mt] = mfma16(av, bv, acc[mt]);
                }
            }
        }
    }
    #pragma unroll
    for (int mt = 0; mt < 2; mt++) {
        #pragma unroll
        for (int r = 0; r < 4; r++) {
            int m = mt * 16 + q * 4 + r;
            if (m < 25)
                dst[((size_t)(b * 25 + m)) * plane + y * width + x0 + x] =
                    acc[mt][r] + b_ce[m];
        }
    }
}

// ---------------------------------------------------------------------------
// K4: softmax over 25, q-split 4-way (64 px x 4 qgroups per block)
// ---------------------------------------------------------------------------
__global__ __launch_bounds__(256) void k_softmax(
        const float* __restrict__ tmp1, const float* __restrict__ tmp2,
        float* __restrict__ kbuf) {
    __shared__ float red[4][64];
    int t = threadIdx.x;
    int tx = t & 63, qg = t >> 6;
    int gp = blockIdx.x * 64 + tx;                // 0..65535
    int b = gp >> 14, p = gp & 16383;
    int i = p >> 7, j = p & 127;
    int pl = (i >> 1) * W + (j >> 1);
    int q0 = qg * 7;
    int nq = (qg < 3) ? 7 : 4;
    float l[7];
    float mx = -1e30f;
    for (int iq = 0; iq < nq; iq++) {
        int qq = q0 + iq;
        l[iq] = tmp1[((size_t)(b * 25 + qq) << 14) + p]
              + tmp2[((size_t)(b * 25 + qq) << 12) + pl];
        mx = fmaxf(mx, l[iq]);
    }
    red[qg][tx] = mx;
    __syncthreads();
    mx = fmaxf(fmaxf(red[0][tx], red[1][tx]), fmaxf(red[2][tx], red[3][tx]));
    float s = 0.f;
    for (int iq = 0; iq < nq; iq++) { l[iq] = __expf(l[iq] - mx); s += l[iq]; }
    __syncthreads();
    red[qg][tx] = s;
    __syncthreads();
    s = red[0][tx] + red[1][tx] + red[2][tx] + red[3][tx];
    float inv = 1.f / s;
    float* kb = kbuf + (size_t)gp * 28;
    for (int iq = 0; iq < nq; iq++) kb[q0 + iq] = l[iq] * inv;
    if (qg == 3) { kb[25] = 0.f; kb[26] = 0.f; kb[27] = 0.f; }
}

// ---------------------------------------------------------------------------
// K5: CARAFE + blend, lo-pixel-centric: 1 thread = 1 lo px x 16 ch x 4 hi px.
//   grid (16 tiles, 16 cg, 4 b); LDS = 16ch x 20x21 halo window of de.
// ---------------------------------------------------------------------------
__global__ __launch_bounds__(256) void k_final(
        const float* __restrict__ en, const float* __restrict__ de,
        const float* __restrict__ kbuf, const float* __restrict__ gate_lr,
        float* __restrict__ out) {
    __shared__ float sde[16][20][21];             // 26.9 KB
    int t = threadIdx.x;
    int tlx = blockIdx.x & 3, tly = blockIdx.x >> 2;
    int c0 = blockIdx.y * 16;
    int b = blockIdx.z;
    int y0 = tly * 16, x0 = tlx * 16;

    const float* dbase = de + ((size_t)b * C + c0) * HW;
    for (int idx = t; idx < 16 * 400; idx += 256) {
        int c = idx / 400, rem = idx % 400;
        int yy0 = rem / 20, xx0 = rem % 20;
        int yy = y0 - 2 + yy0, xx = x0 - 2 + xx0;
        float v = 0.f;
        if ((unsigned)yy < (unsigned)H && (unsigned)xx < (unsigned)W)
            v = dbase[(size_t)c * HW + yy * W + xx];
        sde[c][yy0][xx0] = v;
    }

    int ty = t >> 4, tx = t & 15;
    int yl = y0 + ty, xl = x0 + tx;
    float4 kf[4][7];
    #pragma unroll
    for (int hp = 0; hp < 4; hp++) {
        int ii = 2 * yl + (hp >> 1), jj = 2 * xl + (hp & 1);
        const float4* kb = (const float4*)(
            kbuf + ((size_t)b * HWO + ii * WO + jj) * 28);
        #pragma unroll
        for (int v = 0; v < 7; v++) kf[hp][v] = kb[v];
    }
    float g = gate_lr[b * HW + yl * W + xl];
    float gm = 1.f - g;
    __syncthreads();

    const float* ebase = en + ((size_t)b * C + c0) * HWO;
    float* obase = out + ((size_t)b * C + c0) * HWO;
    for (int c = 0; c < 16; c++) {
        float acc0 = 0.f, acc1 = 0.f, acc2 = 0.f, acc3 = 0.f;
        #pragma unroll
        for (int dy = 0; dy < 5; dy++) {
            #pragma unroll
            for (int dx = 0; dx < 5; dx++) {
                float v = sde[c][ty + dy][tx + dx];
                int k = dy * 5 + dx;
                acc0 += ((const float*)&kf[0][0])[k] * v;
                acc1 += ((const float*)&kf[1][0])[k] * v;
                acc2 += ((const float*)&kf[2][0])[k] * v;
                acc3 += ((const float*)&kf[3][0])[k] * v;
            }
        }
        size_t cc = (size_t)c * HWO;
        float2 e0 = *(const float2*)(ebase + cc + (2 * yl) * WO + 2 * xl);
        float2 e1 = *(const float2*)(ebase + cc + (2 * yl + 1) * WO + 2 * xl);
        float2 o0, o1;
        o0.x = g * e0.x + gm * acc0;  o0.y = g * e0.y + gm * acc1;
        o1.x = g * e1.x + gm * acc2;  o1.y = g * e1.y + gm * acc3;
        *(float2*)(obase + cc + (2 * yl) * WO + 2 * xl) = o0;
        *(float2*)(obase + cc + (2 * yl + 1) * WO + 2 * xl) = o1;
    }
}

extern "C" void kernel_launch(void* const* d_in, const int* in_sizes, int n_in,
                              void* d_out, int out_size, void* d_ws, size_t ws_size,
                              hipStream_t stream) {
    const float* en     = (const float*)d_in[0];
    const float* de     = (const float*)d_in[1];
    const float* w_gate = (const float*)d_in[2];
    const float* b_gate = (const float*)d_in[3];
    const float* w_cen  = (const float*)d_in[4];
    const float* b_cen  = (const float*)d_in[5];
    const float* w_cde  = (const float*)d_in[6];
    const float* w_ce   = (const float*)d_in[7];
    const float* b_ce   = (const float*)d_in[8];
    float* out = (float*)d_out;

    __bf16* wsb     = (__bf16*)d_ws;
    __bf16* wbf_cen = wsb;                   // 16384
    __bf16* wdec5   = wbf_cen + 16384;       // 20480
    __bf16* w3      = wdec5 + 20480;         // 18432
    __bf16* enc_t   = w3 + 18432;            // 4194304
    __bf16* dec_t   = enc_t + 4194304;       // 1048576
    float* wsf     = (float*)((char*)d_ws + (size_t)(16384 + 20480 + 18432
                              + 4194304 + 1048576) * 2);
    float* tmp1    = wsf;                    // 1638400
    float* tmp2    = tmp1 + 1638400;         // 409600
    float* gate_lr = tmp2 + 409600;          // 16384
    float* kbuf    = gate_lr + 16384;        // 1835008

    k_prep2<<<80, 256, 0, stream>>>(w_cen, w_cde, w_gate, w_ce,
                                    wbf_cen, wdec5, w3);
    k_gemm1<<<1280, 256, 0, stream>>>(en, de, wbf_cen, wdec5, b_cen, b_gate,
                                      enc_t, dec_t, gate_lr);
    k_conv3m<<<1280, 256, 0, stream>>>(enc_t, dec_t, w3, b_ce, tmp1, tmp2);
    k_softmax<<<1024, 256, 0, stream>>>(tmp1, tmp2, kbuf);
    k_final<<<dim3(16, 16, 4), 256, 0, stream>>>(en, de, kbuf, gate_lr, out);
}

// Round 5
// 234.829 us; speedup vs baseline: 1.0268x; 1.0268x over previous
//
#include <hip/hip_runtime.h>
#include <math.h>

#define BB 4
#define C 256
#define H 64
#define W 64
#define HW 4096
#define HO 128
#define WO 128
#define HWO 16384
#define EMB 64

typedef __bf16 bf16x8 __attribute__((ext_vector_type(8)));
typedef __bf16 bf16x4 __attribute__((ext_vector_type(4)));
typedef float  f32x4  __attribute__((ext_vector_type(4)));

__device__ __forceinline__ f32x4 mfma16(bf16x8 a, bf16x8 b, f32x4 c) {
    return __builtin_amdgcn_mfma_f32_16x16x32_bf16(a, b, c, 0, 0, 0);
}

// ---------------------------------------------------------------------------
// K1: weight tables (bf16)
//   wbf_cen: [e][c] (=w_cen layout, cast)
//   wdec5:   [5mt][16m][256c]; mt<4 = w_cde; mt=4 row0 = w_gate, rest 0
//   w3:      [tap9][mt2][16m][64e], rows m>=25 zeroed
// ---------------------------------------------------------------------------
__global__ void k_prep2(const float* __restrict__ w_cen,
                        const float* __restrict__ w_cde,
                        const float* __restrict__ w_gate,
                        const float* __restrict__ w_ce,
                        __bf16* __restrict__ wbf_cen,
                        __bf16* __restrict__ wdec5,
                        __bf16* __restrict__ w3) {
    for (int idx = blockIdx.x * blockDim.x + threadIdx.x; idx < 16384;
         idx += gridDim.x * blockDim.x)
        wbf_cen[idx] = (__bf16)w_cen[idx];
    for (int idx = blockIdx.x * blockDim.x + threadIdx.x; idx < 20480;
         idx += gridDim.x * blockDim.x) {
        int c = idx & 255, m = (idx >> 8) & 15;
        float v;
        if (idx < 16384) v = w_cde[idx];
        else             v = (m == 0) ? w_gate[c] : 0.f;
        wdec5[idx] = (__bf16)v;
    }
    for (int idx = blockIdx.x * blockDim.x + threadIdx.x; idx < 18432;
         idx += gridDim.x * blockDim.x) {
        int e = idx & 63;
        int m = (idx >> 6) & 15;
        int mt = (idx >> 10) & 1;
        int tap = idx >> 11;
        int q = mt * 16 + m;
        int dy = tap / 3, dx = tap % 3;
        w3[idx] = (q < 25) ? (__bf16)w_ce[((q * EMB + e) * 3 + dy) * 3 + dx]
                           : (__bf16)0.0f;
    }
}

// ---------------------------------------------------------------------------
// K2: MFMA GEMM Y[px][e] = Wt[e][c]·X[c][px], double-buffered LDS, 128-px
//   tiles. blocks [0,512): enc (+b_cen); [512,640): dec (+gate row)
// ---------------------------------------------------------------------------
__global__ __launch_bounds__(256) void k_gemm1(
        const float* __restrict__ en, const float* __restrict__ de,
        const __bf16* __restrict__ wbf_cen, const __bf16* __restrict__ wdec5,
        const float* __restrict__ b_cen, const float* __restrict__ b_gate,
        __bf16* __restrict__ enc_t, __bf16* __restrict__ dec_t,
        float* __restrict__ gate_lr) {
    __shared__ float xs[2][32][136];              // 34816 B
    int t = threadIdx.x;
    int w = t >> 6, lane = t & 63;
    int n = lane & 15, q = lane >> 4;
    bool isenc = blockIdx.x < 512;
    const float* X; const __bf16* Wt; __bf16* Y; int plane, px0, b;
    if (isenc) {
        int blk = blockIdx.x; b = blk >> 7; px0 = (blk & 127) << 7;
        X = en + (size_t)b * C * HWO; plane = HWO; Wt = wbf_cen;
        Y = enc_t + (size_t)b * HWO * EMB;
    } else {
        int blk = blockIdx.x - 512; b = blk >> 5; px0 = (blk & 31) << 7;
        X = de + (size_t)b * C * HW; plane = HW; Wt = wdec5;
        Y = dec_t + (size_t)b * HW * EMB;
    }
    int scc = t >> 5;                 // staging c row 0..7
    int sp4 = (t & 31) << 2;          // staging px offset
    float4 pre[4];
    #pragma unroll
    for (int i = 0; i < 4; i++)
        pre[i] = *(const float4*)(X + (size_t)(i * 8 + scc) * plane + px0 + sp4);
    #pragma unroll
    for (int i = 0; i < 4; i++)
        *(float4*)(&xs[0][i * 8 + scc][sp4]) = pre[i];
    __syncthreads();

    f32x4 acc[4][2] = {};
    f32x4 accg[2] = {};
    for (int kc = 0; kc < 8; kc++) {
        int cur = kc & 1;
        if (kc < 7) {
            int c1 = (kc + 1) * 32;
            #pragma unroll
            for (int i = 0; i < 4; i++)
                pre[i] = *(const float4*)(X + (size_t)(c1 + i * 8 + scc) * plane
                                          + px0 + sp4);
        }
        int c0 = kc * 32;
        bf16x8 af[4];
        #pragma unroll
        for (int mt = 0; mt < 4; mt++)
            af[mt] = *(const bf16x8*)(Wt + (size_t)(mt * 16 + n) * C + c0 + q * 8);
        bf16x8 bv[2];
        #pragma unroll
        for (int nt = 0; nt < 2; nt++) {
            int px = w * 32 + nt * 16 + n;
            #pragma unroll
            for (int j = 0; j < 8; j++)
                bv[nt][j] = (__bf16)xs[cur][q * 8 + j][px];
        }
        #pragma unroll
        for (int mt = 0; mt < 4; mt++) {
            acc[mt][0] = mfma16(af[mt], bv[0], acc[mt][0]);
            acc[mt][1] = mfma16(af[mt], bv[1], acc[mt][1]);
        }
        if (!isenc) {
            bf16x8 ag = *(const bf16x8*)(Wt + (size_t)(64 + n) * C + c0 + q * 8);
            accg[0] = mfma16(ag, bv[0], accg[0]);
            accg[1] = mfma16(ag, bv[1], accg[1]);
        }
        if (kc < 7) {
            #pragma unroll
            for (int i = 0; i < 4; i++)
                *(float4*)(&xs[cur ^ 1][i * 8 + scc][sp4]) = pre[i];
        }
        __syncthreads();
    }

    #pragma unroll
    for (int nt = 0; nt < 2; nt++) {
        int gpx = px0 + w * 32 + nt * 16 + n;
        #pragma unroll
        for (int mt = 0; mt < 4; mt++) {
            int e0 = mt * 16 + q * 4;
            bf16x4 ov;
            #pragma unroll
            for (int r = 0; r < 4; r++) {
                float bias = isenc ? b_cen[e0 + r] : 0.f;
                ov[r] = (__bf16)(acc[mt][nt][r] + bias);
            }
            *(bf16x4*)(Y + (size_t)gpx * EMB + e0) = ov;
        }
        if (!isenc && q == 0)
            gate_lr[b * HW + gpx] =
                1.f / (1.f + __expf(-(accg[nt][0] + b_gate[0])));
    }
}

// ---------------------------------------------------------------------------
// K3: 3x3 conv 64->25 via MFMA; 3 input rows staged in LDS in fragment order
//     (zero-padded halo). blocks [0,1024): enc_t->tmp1; [1024,1280): dec_t->tmp2
// ---------------------------------------------------------------------------
__global__ __launch_bounds__(256) void k_conv3m(
        const __bf16* __restrict__ enc_t, const __bf16* __restrict__ dec_t,
        const __bf16* __restrict__ w3, const float* __restrict__ b_ce,
        float* __restrict__ tmp1, float* __restrict__ tmp2) {
    __shared__ __bf16 sfr[8 * 3 * 66 * 8];        // 25.3 KB
    int t = threadIdx.x;
    int w = t >> 6, lane = t & 63;
    int n = lane & 15, q = lane >> 4;
    bool hi = blockIdx.x < 1024;
    const __bf16* src; float* dst; int b, y, width, plane, x0;
    if (hi) {
        int blk = blockIdx.x; b = blk >> 8; int r = blk & 255;
        y = r >> 1; x0 = (r & 1) * 64;
        width = WO; plane = HWO;
        src = enc_t + (size_t)b * HWO * EMB; dst = tmp1;
    } else {
        int blk = blockIdx.x - 1024; b = blk >> 6; y = blk & 63; x0 = 0;
        width = W; plane = HW;
        src = dec_t + (size_t)b * HW * EMB; dst = tmp2;
    }
    bf16x8 zf;
    #pragma unroll
    for (int j = 0; j < 8; j++) zf[j] = (__bf16)0.0f;
    for (int idx = t; idx < 1584; idx += 256) {
        int f = idx & 7;
        int rem = idx >> 3;
        int xloc = rem % 66, row = rem / 66;
        int yy = y + row - 1, xg = x0 - 1 + xloc;
        bf16x8 v = zf;
        if ((unsigned)yy < (unsigned)width && (unsigned)xg < (unsigned)width)
            v = *(const bf16x8*)(src + ((size_t)yy * width + xg) * EMB + f * 8);
        *(bf16x8*)(sfr + (((f * 3) + row) * 66 + xloc) * 8) = v;
    }
    __syncthreads();

    int x = w * 16 + n;
    f32x4 acc[2] = {};
    #pragma unroll
    for (int row = 0; row < 3; row++) {
        #pragma unroll
        for (int dx = 0; dx < 3; dx++) {
            int tap = row * 3 + dx;
            #pragma unroll
            for (int kc = 0; kc < 2; kc++) {
                bf16x8 bv = *(const bf16x8*)(
                    sfr + ((((kc * 4 + q) * 3) + row) * 66 + x + dx) * 8);
                #pragma unroll
                for (int mt = 0; mt < 2; mt++) {
                    bf16x8 av = *(const bf16x8*)(
                        w3 + ((tap * 2 + mt) * 16 + n) * EMB + kc * 32 + q * 8);
                    acc[mt] = mfma16(av, bv, acc[mt]);
                }
            }
        }
    }
    #pragma unroll
    for (int mt = 0; mt < 2; mt++) {
        #pragma unroll
        for (int r = 0; r < 4; r++) {
            int m = mt * 16 + q * 4 + r;
            if (m < 25)
                dst[((size_t)(b * 25 + m)) * plane + y * width + x0 + x] =
                    acc[mt][r] + b_ce[m];
        }
    }
}

// ---------------------------------------------------------------------------
// K4: softmax over 25, q-split 4-way (64 px x 4 qgroups per block)
// ---------------------------------------------------------------------------
__global__ __launch_bounds__(256) void k_softmax(
        const float* __restrict__ tmp1, const float* __restrict__ tmp2,
        float* __restrict__ kbuf) {
    __shared__ float red[4][64];
    int t = threadIdx.x;
    int tx = t & 63, qg = t >> 6;
    int gp = blockIdx.x * 64 + tx;                // 0..65535
    int b = gp >> 14, p = gp & 16383;
    int i = p >> 7, j = p & 127;
    int pl = (i >> 1) * W + (j >> 1);
    int q0 = qg * 7;
    int nq = (qg < 3) ? 7 : 4;
    float l[7];
    float mx = -1e30f;
    for (int iq = 0; iq < nq; iq++) {
        int qq = q0 + iq;
        l[iq] = tmp1[((size_t)(b * 25 + qq) << 14) + p]
              + tmp2[((size_t)(b * 25 + qq) << 12) + pl];
        mx = fmaxf(mx, l[iq]);
    }
    red[qg][tx] = mx;
    __syncthreads();
    mx = fmaxf(fmaxf(red[0][tx], red[1][tx]), fmaxf(red[2][tx], red[3][tx]));
    float s = 0.f;
    for (int iq = 0; iq < nq; iq++) { l[iq] = __expf(l[iq] - mx); s += l[iq]; }
    __syncthreads();
    red[qg][tx] = s;
    __syncthreads();
    s = red[0][tx] + red[1][tx] + red[2][tx] + red[3][tx];
    float inv = 1.f / s;
    float* kb = kbuf + (size_t)gp * 28;
    for (int iq = 0; iq < nq; iq++) kb[q0 + iq] = l[iq] * inv;
    if (qg == 3) { kb[25] = 0.f; kb[26] = 0.f; kb[27] = 0.f; }
}

// ---------------------------------------------------------------------------
// K5: CARAFE + blend. Lo tile 32x8 per block (1 thread = 1 lo px, 4 hi px,
//   16 ch). Wave = 2 full 32-px rows -> sde reads are 2 lanes/bank (free).
// ---------------------------------------------------------------------------
#define NCH 16
__global__ __launch_bounds__(256) void k_final(
        const float* __restrict__ en, const float* __restrict__ de,
        const float* __restrict__ kbuf, const float* __restrict__ gate_lr,
        float* __restrict__ out) {
    __shared__ float sde[NCH][12][36];            // 27648 B
    int t = threadIdx.x;
    int x0 = (blockIdx.x & 1) * 32, y0 = (blockIdx.x >> 1) * 8;
    int c0 = blockIdx.y * NCH;
    int b = blockIdx.z;

    const float* dbase = de + ((size_t)b * C + c0) * HW;
    for (int idx = t; idx < NCH * 432; idx += 256) {
        int c = idx / 432, rem = idx % 432;
        int row = rem / 36, col = rem % 36;
        int yy = y0 - 2 + row, xx = x0 - 2 + col;
        float v = 0.f;
        if ((unsigned)yy < (unsigned)H && (unsigned)xx < (unsigned)W)
            v = dbase[(size_t)c * HW + yy * W + xx];
        sde[c][row][col] = v;
    }

    int tx = t & 31, ty = t >> 5;
    int yl = y0 + ty, xl = x0 + tx;
    float kern[4][25];
    #pragma unroll
    for (int hp = 0; hp < 4; hp++) {
        int ii = 2 * yl + (hp >> 1), jj = 2 * xl + (hp & 1);
        const float* kb = kbuf + ((size_t)b * HWO + ii * WO + jj) * 28;
        #pragma unroll
        for (int v = 0; v < 6; v++)
            *(float4*)&kern[hp][v * 4] = *(const float4*)(kb + v * 4);
        kern[hp][24] = kb[24];
    }
    float g = gate_lr[b * HW + yl * W + xl];
    float gm = 1.f - g;
    __syncthreads();

    const float* ebase = en + ((size_t)b * C + c0) * HWO + (2 * yl) * WO + 2 * xl;
    float* obase = out + ((size_t)b * C + c0) * HWO + (2 * yl) * WO + 2 * xl;
    #pragma unroll 2
    for (int c = 0; c < NCH; c++) {
        float a0 = 0.f, a1 = 0.f, a2 = 0.f, a3 = 0.f;
        #pragma unroll
        for (int dy = 0; dy < 5; dy++) {
            #pragma unroll
            for (int dx = 0; dx < 5; dx++) {
                float v = sde[c][ty + dy][tx + dx];
                int k = dy * 5 + dx;
                a0 += kern[0][k] * v;
                a1 += kern[1][k] * v;
                a2 += kern[2][k] * v;
                a3 += kern[3][k] * v;
            }
        }
        size_t cc = (size_t)c * HWO;
        float2 e0 = *(const float2*)(ebase + cc);
        float2 e1 = *(const float2*)(ebase + cc + WO);
        float2 o0, o1;
        o0.x = g * e0.x + gm * a0;  o0.y = g * e0.y + gm * a1;
        o1.x = g * e1.x + gm * a2;  o1.y = g * e1.y + gm * a3;
        *(float2*)(obase + cc) = o0;
        *(float2*)(obase + cc + WO) = o1;
    }
}

extern "C" void kernel_launch(void* const* d_in, const int* in_sizes, int n_in,
                              void* d_out, int out_size, void* d_ws, size_t ws_size,
                              hipStream_t stream) {
    const float* en     = (const float*)d_in[0];
    const float* de     = (const float*)d_in[1];
    const float* w_gate = (const float*)d_in[2];
    const float* b_gate = (const float*)d_in[3];
    const float* w_cen  = (const float*)d_in[4];
    const float* b_cen  = (const float*)d_in[5];
    const float* w_cde  = (const float*)d_in[6];
    const float* w_ce   = (const float*)d_in[7];
    const float* b_ce   = (const float*)d_in[8];
    float* out = (float*)d_out;

    __bf16* wsb     = (__bf16*)d_ws;
    __bf16* wbf_cen = wsb;                   // 16384
    __bf16* wdec5   = wbf_cen + 16384;       // 20480
    __bf16* w3      = wdec5 + 20480;         // 18432
    __bf16* enc_t   = w3 + 18432;            // 4194304
    __bf16* dec_t   = enc_t + 4194304;       // 1048576
    float* wsf     = (float*)((char*)d_ws + (size_t)(16384 + 20480 + 18432
                              + 4194304 + 1048576) * 2);
    float* tmp1    = wsf;                    // 1638400
    float* tmp2    = tmp1 + 1638400;         // 409600
    float* gate_lr = tmp2 + 409600;          // 16384
    float* kbuf    = gate_lr + 16384;        // 1835008

    k_prep2<<<80, 256, 0, stream>>>(w_cen, w_cde, w_gate, w_ce,
                                    wbf_cen, wdec5, w3);
    k_gemm1<<<640, 256, 0, stream>>>(en, de, wbf_cen, wdec5, b_cen, b_gate,
                                     enc_t, dec_t, gate_lr);
    k_conv3m<<<1280, 256, 0, stream>>>(enc_t, dec_t, w3, b_ce, tmp1, tmp2);
    k_softmax<<<1024, 256, 0, stream>>>(tmp1, tmp2, kbuf);
    k_final<<<dim3(16, 16, 4), 256, 0, stream>>>(en, de, kbuf, gate_lr, out);
}